// Round 1
// baseline (82.468 us; speedup 1.0000x reference)
//
#include <hip/hip_runtime.h>
#include <stdint.h>

// Problem constants
#define MDIM 8192   // batch
#define KDIM 512    // input size
#define TDIM 2080   // tril param count (64*65/2)
#define NPAD 2176   // TDIM padded to multiple of 128 (17*128)
#define MSZ  64     // matrix size

typedef __attribute__((ext_vector_type(8))) __bf16 bf16x8;
typedef __attribute__((ext_vector_type(4))) float  f32x4;

__device__ __forceinline__ unsigned short f2bf(float f) {
    unsigned int u = __float_as_uint(f);
    u += 0x7fffu + ((u >> 16) & 1u);   // round-to-nearest-even
    return (unsigned short)(u >> 16);
}

// ---------------- convert kernels ----------------
__global__ __launch_bounds__(256) void convert_x_kernel(const float* __restrict__ x,
                                                        unsigned short* __restrict__ xb) {
    int idx = blockIdx.x * 256 + threadIdx.x;            // float4 index
    float4 v = reinterpret_cast<const float4*>(x)[idx];
    ushort4 o = make_ushort4(f2bf(v.x), f2bf(v.y), f2bf(v.z), f2bf(v.w));
    reinterpret_cast<ushort4*>(xb)[idx] = o;
}

__global__ __launch_bounds__(256) void convert_w_kernel(const float* __restrict__ W,
                                                        unsigned short* __restrict__ wb) {
    int idx = blockIdx.x * 256 + threadIdx.x;            // float4 index in padded [NPAD*KDIM]
    int n = (idx * 4) >> 9;                              // row (KDIM=512)
    ushort4 o = make_ushort4(0, 0, 0, 0);
    if (n < TDIM) {
        float4 v = reinterpret_cast<const float4*>(W)[idx];
        o = make_ushort4(f2bf(v.x), f2bf(v.y), f2bf(v.z), f2bf(v.w));
    }
    reinterpret_cast<ushort4*>(wb)[idx] = o;
}

// ---------------- shared helpers ----------------
typedef __attribute__((address_space(1))) void as1_void;
typedef __attribute__((address_space(3))) void as3_void;

__device__ __forceinline__ void gload_lds16(const void* g, void* l) {
    // 16B direct global->LDS; dest is wave-uniform base + lane*16
    __builtin_amdgcn_global_load_lds((as1_void*)(void*)g, (as3_void*)l, 16, 0, 0);
}

// LDS tiles are [rows][64] bf16 (128B rows), XOR-swizzled: byte ^= (row&7)<<4
__device__ __forceinline__ bf16x8 frag_load(const unsigned short* base, int row, int kbyte) {
    kbyte ^= (row & 7) << 4;
    return *reinterpret_cast<const bf16x8*>(reinterpret_cast<const char*>(base) + row * 128 + kbyte);
}

// tril row index from linear tril index n
__device__ __forceinline__ int tril_row(int n) {
    int i = (int)((sqrtf((float)(8 * n + 1)) - 1.0f) * 0.5f);
    while ((i + 1) * (i + 2) / 2 <= n) ++i;
    while (i * (i + 1) / 2 > n) --i;
    return i;
}

// ---------------- GEMM1: chol = x @ W^T + b, diag-ReLU, store bf16 ----------------
__global__ __launch_bounds__(256) void gemm_kernel(const unsigned short* __restrict__ xb,
                                                   const unsigned short* __restrict__ wb,
                                                   const float* __restrict__ bias,
                                                   unsigned short* __restrict__ chol) {
    __shared__ __align__(16) unsigned short As[128 * 64];
    __shared__ __align__(16) unsigned short Bs[128 * 64];
    const int tid  = threadIdx.x;
    const int lane = tid & 63;
    const int wave = tid >> 6;
    const int m0 = blockIdx.y * 128;
    const int n0 = blockIdx.x * 128;
    const int wm = (wave >> 1) * 64;   // wave row offset in tile
    const int wn = (wave & 1) * 64;    // wave col offset in tile
    const int lr = lane & 15;
    const int lq = lane >> 4;

    f32x4 acc[4][4];
    f32x4 zero = {0.f, 0.f, 0.f, 0.f};
#pragma unroll
    for (int i = 0; i < 4; ++i)
#pragma unroll
        for (int j = 0; j < 4; ++j) acc[i][j] = zero;

    for (int k0 = 0; k0 < KDIM; k0 += 64) {
        const unsigned short* ga = xb + (size_t)m0 * KDIM + k0;
        const unsigned short* gb = wb + (size_t)n0 * KDIM + k0;
        // stage A tile: 128x64 bf16 = 1024 x 16B chunks; pre-swizzled global source
#pragma unroll
        for (int c = 0; c < 4; ++c) {
            int flat = c * 256 + tid;
            int row  = flat >> 3;
            int ch   = (flat & 7) ^ (row & 7);
            unsigned short* lb = (unsigned short*)As + (size_t)(c * 256 + (tid & 192)) * 8;
            gload_lds16(ga + row * KDIM + ch * 8, lb);
        }
#pragma unroll
        for (int c = 0; c < 4; ++c) {
            int flat = c * 256 + tid;
            int row  = flat >> 3;
            int ch   = (flat & 7) ^ (row & 7);
            unsigned short* lb = (unsigned short*)Bs + (size_t)(c * 256 + (tid & 192)) * 8;
            gload_lds16(gb + row * KDIM + ch * 8, lb);
        }
        __syncthreads();   // drains vmcnt -> staged data visible
#pragma unroll
        for (int kk = 0; kk < 2; ++kk) {
            bf16x8 af[4], bf[4];
            int kb = kk * 64 + lq * 16;
#pragma unroll
            for (int i = 0; i < 4; ++i) {
                af[i] = frag_load(As, wm + i * 16 + lr, kb);
                bf[i] = frag_load(Bs, wn + i * 16 + lr, kb);
            }
#pragma unroll
            for (int mi = 0; mi < 4; ++mi)
#pragma unroll
                for (int ni = 0; ni < 4; ++ni)
                    acc[mi][ni] = __builtin_amdgcn_mfma_f32_16x16x32_bf16(af[mi], bf[ni], acc[mi][ni], 0, 0, 0);
        }
        __syncthreads();   // all waves done reading before next stage overwrites
    }

    // epilogue: bias + diag ReLU + bf16 store
#pragma unroll
    for (int ni = 0; ni < 4; ++ni) {
        int n = n0 + wn + ni * 16 + lr;
        float bv = 0.f;
        bool isdiag = false;
        if (n < TDIM) {
            bv = bias[n];
            int i = tril_row(n);
            isdiag = (n - i * (i + 1) / 2 == i);
        }
#pragma unroll
        for (int mi = 0; mi < 4; ++mi) {
#pragma unroll
            for (int r = 0; r < 4; ++r) {
                int m = m0 + wm + mi * 16 + lq * 4 + r;   // C/D layout: col=lane&15, row=(lane>>4)*4+reg
                float v = acc[mi][ni][r] + bv;
                if (isdiag && v < 0.f) v = 0.f;
                chol[(size_t)m * NPAD + n] = f2bf(v);
            }
        }
    }
}

// ---------------- SYRK: out[b] = L @ L^T ----------------
__device__ __forceinline__ void lds_store_swz(unsigned short* L, int i, int j, unsigned short v) {
    int ch   = ((j >> 3) ^ i) & 7;                       // swizzled 16B chunk
    int addr = i * 128 + (ch << 4) + ((j & 7) * 2);
    *reinterpret_cast<unsigned short*>(reinterpret_cast<char*>(L) + addr) = v;
}

__global__ __launch_bounds__(256) void syrk_kernel(const unsigned short* __restrict__ chol,
                                                   float* __restrict__ out) {
    __shared__ __align__(16) unsigned short Ls[4][64 * 64];
    const int tid  = threadIdx.x;
    const int lane = tid & 63;
    const int wave = tid >> 6;
    const int batch = blockIdx.x * 4 + wave;
    unsigned short* L = Ls[wave];

    // zero the tile (upper triangle must be 0)
#pragma unroll
    for (int c = 0; c < 8; ++c)
        *reinterpret_cast<int4*>(reinterpret_cast<char*>(L) + (c * 64 + lane) * 16) = make_int4(0, 0, 0, 0);
    __syncthreads();

    // scatter chol row into lower triangle (coalesced dword reads, 2 entries each)
    const unsigned int* row = reinterpret_cast<const unsigned int*>(chol + (size_t)batch * NPAD);
    for (int t = lane; t < TDIM / 2; t += 64) {
        unsigned int v = row[t];
        int n = 2 * t;
        int i = tril_row(n);
        int j = n - i * (i + 1) / 2;
        lds_store_swz(L, i, j, (unsigned short)(v & 0xffffu));
        int i2 = i, j2 = j + 1;
        if (j2 > i2) { i2 = i + 1; j2 = 0; }
        lds_store_swz(L, i2, j2, (unsigned short)(v >> 16));
    }
    __syncthreads();

    const int lr = lane & 15;
    const int lq = lane >> 4;
    // A and B fragments are identical reads (out = L @ L^T, B^T-form)
    bf16x8 fr[4][2];
#pragma unroll
    for (int i = 0; i < 4; ++i)
#pragma unroll
        for (int kk = 0; kk < 2; ++kk)
            fr[i][kk] = frag_load(L, i * 16 + lr, kk * 64 + lq * 16);

    f32x4 acc[4][4];
    f32x4 zero = {0.f, 0.f, 0.f, 0.f};
#pragma unroll
    for (int i = 0; i < 4; ++i)
#pragma unroll
        for (int j = 0; j < 4; ++j) acc[i][j] = zero;

#pragma unroll
    for (int mi = 0; mi < 4; ++mi)
#pragma unroll
        for (int ni = 0; ni < 4; ++ni)
#pragma unroll
            for (int kk = 0; kk < 2; ++kk)
                acc[mi][ni] = __builtin_amdgcn_mfma_f32_16x16x32_bf16(fr[mi][kk], fr[ni][kk], acc[mi][ni], 0, 0, 0);

    float* ob = out + (size_t)batch * (MSZ * MSZ);
#pragma unroll
    for (int mi = 0; mi < 4; ++mi)
#pragma unroll
        for (int ni = 0; ni < 4; ++ni)
#pragma unroll
            for (int r = 0; r < 4; ++r)
                ob[(mi * 16 + lq * 4 + r) * MSZ + ni * 16 + lr] = acc[mi][ni][r];
}

// ---------------- launch ----------------
extern "C" void kernel_launch(void* const* d_in, const int* in_sizes, int n_in,
                              void* d_out, int out_size, void* d_ws, size_t ws_size,
                              hipStream_t stream) {
    (void)in_sizes; (void)n_in; (void)out_size; (void)ws_size;
    const float* x = (const float*)d_in[0];   // [8192,512]
    const float* W = (const float*)d_in[1];   // [2080,512]
    const float* b = (const float*)d_in[2];   // [2080]
    float* out = (float*)d_out;               // [8192,64,64]

    unsigned short* xb   = (unsigned short*)d_ws;                 // 8192*512 bf16
    unsigned short* wb   = xb + (size_t)MDIM * KDIM;              // 2176*512 bf16 (padded)
    unsigned short* chol = wb + (size_t)NPAD * KDIM;              // 8192*2176 bf16

    convert_x_kernel<<<dim3(MDIM * KDIM / 1024), dim3(256), 0, stream>>>(x, xb);
    convert_w_kernel<<<dim3(NPAD * KDIM / 1024), dim3(256), 0, stream>>>(W, wb);
    gemm_kernel<<<dim3(NPAD / 128, MDIM / 128), dim3(256), 0, stream>>>(xb, wb, b, chol);
    syrk_kernel<<<dim3(MDIM / 4), dim3(256), 0, stream>>>(chol, out);
}

// Round 2
// 81.915 us; speedup vs baseline: 1.0068x; 1.0068x over previous
//
#include <hip/hip_runtime.h>
#include <stdint.h>

// Problem constants
#define MDIM 8192   // batch
#define KDIM 512    // input size
#define TDIM 2080   // tril param count (64*65/2)
#define NPAD 2176   // TDIM padded to multiple of 128 (17*128)
#define MSZ  64     // matrix size

typedef __attribute__((ext_vector_type(8))) __bf16 bf16x8;
typedef __attribute__((ext_vector_type(4))) float  f32x4;

__device__ __forceinline__ unsigned short f2bf(float f) {
    unsigned int u = __float_as_uint(f);
    u += 0x7fffu + ((u >> 16) & 1u);   // round-to-nearest-even
    return (unsigned short)(u >> 16);
}

// ---------------- fused convert kernel (x and W in one dispatch) ----------------
#define NX4 (MDIM * KDIM / 4)        // 1048576 float4 chunks of x
#define NW4 (NPAD * KDIM / 4)        // 278528 float4 chunks of padded W

__global__ __launch_bounds__(256) void convert_kernel(const float* __restrict__ x,
                                                      const float* __restrict__ W,
                                                      unsigned short* __restrict__ xb,
                                                      unsigned short* __restrict__ wb) {
    int idx = blockIdx.x * 256 + threadIdx.x;
    if (idx < NX4) {
        float4 v = reinterpret_cast<const float4*>(x)[idx];
        reinterpret_cast<ushort4*>(xb)[idx] =
            make_ushort4(f2bf(v.x), f2bf(v.y), f2bf(v.z), f2bf(v.w));
    } else {
        int j = idx - NX4;
        if (j >= NW4) return;
        int n = (j * 4) >> 9;                            // W row (KDIM=512)
        ushort4 o = make_ushort4(0, 0, 0, 0);
        if (n < TDIM) {
            float4 v = reinterpret_cast<const float4*>(W)[j];
            o = make_ushort4(f2bf(v.x), f2bf(v.y), f2bf(v.z), f2bf(v.w));
        }
        reinterpret_cast<ushort4*>(wb)[j] = o;
    }
}

// ---------------- shared helpers ----------------
typedef __attribute__((address_space(1))) void as1_void;
typedef __attribute__((address_space(3))) void as3_void;

__device__ __forceinline__ void gload_lds16(const void* g, void* l) {
    // 16B direct global->LDS; dest is wave-uniform base + lane*16
    __builtin_amdgcn_global_load_lds((as1_void*)(void*)g, (as3_void*)l, 16, 0, 0);
}

// LDS tiles are [rows][64] bf16 (128B rows), XOR-swizzled: byte ^= (row&7)<<4
__device__ __forceinline__ bf16x8 frag_load(const unsigned short* base, int row, int kbyte) {
    kbyte ^= (row & 7) << 4;
    return *reinterpret_cast<const bf16x8*>(reinterpret_cast<const char*>(base) + row * 128 + kbyte);
}

// tril row index from linear tril index n
__device__ __forceinline__ int tril_row(int n) {
    int i = (int)((sqrtf((float)(8 * n + 1)) - 1.0f) * 0.5f);
    while ((i + 1) * (i + 2) / 2 <= n) ++i;
    while (i * (i + 1) / 2 > n) --i;
    return i;
}

// ---------------- GEMM1: chol = x @ W^T + b, diag-ReLU, store bf16 ----------------
__global__ __launch_bounds__(256) void gemm_kernel(const unsigned short* __restrict__ xb,
                                                   const unsigned short* __restrict__ wb,
                                                   const float* __restrict__ bias,
                                                   unsigned short* __restrict__ chol) {
    __shared__ __align__(16) unsigned short As[128 * 64];
    __shared__ __align__(16) unsigned short Bs[128 * 64];
    const int tid  = threadIdx.x;
    const int lane = tid & 63;
    const int wave = tid >> 6;
    const int m0 = blockIdx.y * 128;
    const int n0 = blockIdx.x * 128;
    const int wm = (wave >> 1) * 64;   // wave row offset in tile
    const int wn = (wave & 1) * 64;    // wave col offset in tile
    const int lr = lane & 15;
    const int lq = lane >> 4;

    f32x4 acc[4][4];
    f32x4 zero = {0.f, 0.f, 0.f, 0.f};
#pragma unroll
    for (int i = 0; i < 4; ++i)
#pragma unroll
        for (int j = 0; j < 4; ++j) acc[i][j] = zero;

    for (int k0 = 0; k0 < KDIM; k0 += 64) {
        const unsigned short* ga = xb + (size_t)m0 * KDIM + k0;
        const unsigned short* gb = wb + (size_t)n0 * KDIM + k0;
        // stage A tile: 128x64 bf16 = 1024 x 16B chunks; pre-swizzled global source
#pragma unroll
        for (int c = 0; c < 4; ++c) {
            int flat = c * 256 + tid;
            int row  = flat >> 3;
            int ch   = (flat & 7) ^ (row & 7);
            unsigned short* lb = (unsigned short*)As + (size_t)(c * 256 + (tid & 192)) * 8;
            gload_lds16(ga + row * KDIM + ch * 8, lb);
        }
#pragma unroll
        for (int c = 0; c < 4; ++c) {
            int flat = c * 256 + tid;
            int row  = flat >> 3;
            int ch   = (flat & 7) ^ (row & 7);
            unsigned short* lb = (unsigned short*)Bs + (size_t)(c * 256 + (tid & 192)) * 8;
            gload_lds16(gb + row * KDIM + ch * 8, lb);
        }
        __syncthreads();   // drains vmcnt -> staged data visible
#pragma unroll
        for (int kk = 0; kk < 2; ++kk) {
            bf16x8 af[4], bf[4];
            int kb = kk * 64 + lq * 16;
#pragma unroll
            for (int i = 0; i < 4; ++i) {
                af[i] = frag_load(As, wm + i * 16 + lr, kb);
                bf[i] = frag_load(Bs, wn + i * 16 + lr, kb);
            }
#pragma unroll
            for (int mi = 0; mi < 4; ++mi)
#pragma unroll
                for (int ni = 0; ni < 4; ++ni)
                    acc[mi][ni] = __builtin_amdgcn_mfma_f32_16x16x32_bf16(af[mi], bf[ni], acc[mi][ni], 0, 0, 0);
        }
        __syncthreads();   // all waves done reading before next stage overwrites
    }

    // epilogue: bias + diag ReLU + bf16 store
#pragma unroll
    for (int ni = 0; ni < 4; ++ni) {
        int n = n0 + wn + ni * 16 + lr;
        float bv = 0.f;
        bool isdiag = false;
        if (n < TDIM) {
            bv = bias[n];
            int i = tril_row(n);
            isdiag = (n - i * (i + 1) / 2 == i);
        }
#pragma unroll
        for (int mi = 0; mi < 4; ++mi) {
#pragma unroll
            for (int r = 0; r < 4; ++r) {
                int m = m0 + wm + mi * 16 + lq * 4 + r;   // C/D layout: col=lane&15, row=(lane>>4)*4+reg
                float v = acc[mi][ni][r] + bv;
                if (isdiag && v < 0.f) v = 0.f;
                chol[(size_t)m * NPAD + n] = f2bf(v);
            }
        }
    }
}

// ---------------- SYRK: out[b] = L @ L^T ----------------
__device__ __forceinline__ void lds_store_swz(unsigned short* L, int i, int j, unsigned short v) {
    int ch   = ((j >> 3) ^ i) & 7;                       // swizzled 16B chunk
    int addr = i * 128 + (ch << 4) + ((j & 7) * 2);
    *reinterpret_cast<unsigned short*>(reinterpret_cast<char*>(L) + addr) = v;
}

__global__ __launch_bounds__(256) void syrk_kernel(const unsigned short* __restrict__ chol,
                                                   float* __restrict__ out) {
    __shared__ __align__(16) unsigned short Ls[4][64 * 64];
    const int tid  = threadIdx.x;
    const int lane = tid & 63;
    const int wave = tid >> 6;
    const int batch = blockIdx.x * 4 + wave;
    unsigned short* L = Ls[wave];

    // Issue all chol-row loads up front (static-indexed reg array; one vmcnt
    // wait instead of 17 serial load->use latencies). 1040 dwords / 64 lanes.
    const unsigned int* row = reinterpret_cast<const unsigned int*>(chol + (size_t)batch * NPAD);
    unsigned int vals[17];
#pragma unroll
    for (int c = 0; c < 17; ++c) {
        int t = lane + c * 64;
        vals[c] = (t < TDIM / 2) ? row[t] : 0u;
    }

    // zero the tile (upper triangle must be 0) — wave-local LDS only
#pragma unroll
    for (int c = 0; c < 8; ++c)
        *reinterpret_cast<int4*>(reinterpret_cast<char*>(L) + (c * 64 + lane) * 16) = make_int4(0, 0, 0, 0);
    __builtin_amdgcn_sched_barrier(0);   // pin zero-writes before scatter-writes

    // scatter chol row into lower triangle
#pragma unroll
    for (int c = 0; c < 17; ++c) {
        int t = lane + c * 64;
        if (t < TDIM / 2) {
            unsigned int v = vals[c];
            int n = 2 * t;
            int i = tril_row(n);
            int j = n - i * (i + 1) / 2;
            lds_store_swz(L, i, j, (unsigned short)(v & 0xffffu));
            int i2 = i, j2 = j + 1;
            if (j2 > i2) { i2 = i + 1; j2 = 0; }
            lds_store_swz(L, i2, j2, (unsigned short)(v >> 16));
        }
    }
    // wave-local write->read ordering (no inter-wave sharing -> no s_barrier)
    asm volatile("s_waitcnt lgkmcnt(0)" ::: "memory");
    __builtin_amdgcn_sched_barrier(0);

    const int lr = lane & 15;
    const int lq = lane >> 4;
    // A and B fragments are identical reads (out = L @ L^T, B^T-form)
    bf16x8 fr[4][2];
#pragma unroll
    for (int i = 0; i < 4; ++i)
#pragma unroll
        for (int kk = 0; kk < 2; ++kk)
            fr[i][kk] = frag_load(L, i * 16 + lr, kk * 64 + lq * 16);

    f32x4 acc[4][4];
    f32x4 zero = {0.f, 0.f, 0.f, 0.f};
#pragma unroll
    for (int i = 0; i < 4; ++i)
#pragma unroll
        for (int j = 0; j < 4; ++j) acc[i][j] = zero;

#pragma unroll
    for (int mi = 0; mi < 4; ++mi)
#pragma unroll
        for (int ni = 0; ni < 4; ++ni)
#pragma unroll
            for (int kk = 0; kk < 2; ++kk)
                acc[mi][ni] = __builtin_amdgcn_mfma_f32_16x16x32_bf16(fr[mi][kk], fr[ni][kk], acc[mi][ni], 0, 0, 0);

    // out is symmetric: store acc[mi][ni] at the TRANSPOSED location so the 4
    // accumulator regs are contiguous -> 16x global_store_dwordx4 (was 64x dword)
    float* ob = out + (size_t)batch * (MSZ * MSZ);
#pragma unroll
    for (int mi = 0; mi < 4; ++mi)
#pragma unroll
        for (int ni = 0; ni < 4; ++ni)
            *reinterpret_cast<f32x4*>(ob + (ni * 16 + lr) * MSZ + mi * 16 + lq * 4) = acc[mi][ni];
}

// ---------------- launch ----------------
extern "C" void kernel_launch(void* const* d_in, const int* in_sizes, int n_in,
                              void* d_out, int out_size, void* d_ws, size_t ws_size,
                              hipStream_t stream) {
    (void)in_sizes; (void)n_in; (void)out_size; (void)ws_size;
    const float* x = (const float*)d_in[0];   // [8192,512]
    const float* W = (const float*)d_in[1];   // [2080,512]
    const float* b = (const float*)d_in[2];   // [2080]
    float* out = (float*)d_out;               // [8192,64,64]

    unsigned short* xb   = (unsigned short*)d_ws;                 // 8192*512 bf16
    unsigned short* wb   = xb + (size_t)MDIM * KDIM;              // 2176*512 bf16 (padded)
    unsigned short* chol = wb + (size_t)NPAD * KDIM;              // 8192*2176 bf16

    int conv_blocks = (NX4 + NW4 + 255) / 256;
    convert_kernel<<<dim3(conv_blocks), dim3(256), 0, stream>>>(x, W, xb, wb);
    gemm_kernel<<<dim3(NPAD / 128, MDIM / 128), dim3(256), 0, stream>>>(xb, wb, b, chol);
    syrk_kernel<<<dim3(MDIM / 4), dim3(256), 0, stream>>>(chol, out);
}

// Round 3
// 74.052 us; speedup vs baseline: 1.1136x; 1.1062x over previous
//
#include <hip/hip_runtime.h>
#include <stdint.h>

// Problem constants
#define MDIM 8192   // batch
#define KDIM 512    // input size
#define TDIM 2080   // tril param count (64*65/2)
#define NPAD 2176   // TDIM padded to multiple of 128 (17*128)
#define MSZ  64     // matrix size

typedef __attribute__((ext_vector_type(8))) __bf16 bf16x8;
typedef __attribute__((ext_vector_type(4))) float  f32x4;

__device__ __forceinline__ unsigned short f2bf(float f) {
    unsigned int u = __float_as_uint(f);
    u += 0x7fffu + ((u >> 16) & 1u);   // round-to-nearest-even
    return (unsigned short)(u >> 16);
}

// tril row index from linear tril index n
__device__ __forceinline__ int tril_row(int n) {
    int i = (int)((sqrtf((float)(8 * n + 1)) - 1.0f) * 0.5f);
    while ((i + 1) * (i + 2) / 2 <= n) ++i;
    while (i * (i + 1) / 2 > n) --i;
    return i;
}

// ---------------- fused convert kernel (x, W, bias/diag tables) ----------------
#define NX4 (MDIM * KDIM / 4)        // 1048576 float4 chunks of x
#define NW4 (NPAD * KDIM / 4)        // 278528 float4 chunks of padded W
#define NT4 (NPAD / 4)               // 544 table chunks

__global__ __launch_bounds__(256) void convert_kernel(const float* __restrict__ x,
                                                      const float* __restrict__ W,
                                                      const float* __restrict__ b,
                                                      unsigned short* __restrict__ xb,
                                                      unsigned short* __restrict__ wb,
                                                      float* __restrict__ biasf,
                                                      float* __restrict__ diagm) {
    int idx = blockIdx.x * 256 + threadIdx.x;
    if (idx < NX4) {
        float4 v = reinterpret_cast<const float4*>(x)[idx];
        reinterpret_cast<ushort4*>(xb)[idx] =
            make_ushort4(f2bf(v.x), f2bf(v.y), f2bf(v.z), f2bf(v.w));
    } else if (idx < NX4 + NW4) {
        int j = idx - NX4;
        int n = (j * 4) >> 9;                            // W row (KDIM=512)
        ushort4 o = make_ushort4(0, 0, 0, 0);
        if (n < TDIM) {
            float4 v = reinterpret_cast<const float4*>(W)[j];
            o = make_ushort4(f2bf(v.x), f2bf(v.y), f2bf(v.z), f2bf(v.w));
        }
        reinterpret_cast<ushort4*>(wb)[j] = o;
    } else {
        int t = idx - NX4 - NW4;
        if (t < NT4) {
#pragma unroll
            for (int r = 0; r < 4; ++r) {
                int n = t * 4 + r;
                float bv = 0.f, dm = 0.f;
                if (n < TDIM) {
                    bv = b[n];
                    int i = tril_row(n);
                    dm = (n - i * (i + 1) / 2 == i) ? 1.f : 0.f;
                }
                biasf[n] = bv;
                diagm[n] = dm;
            }
        }
    }
}

// ---------------- shared helpers ----------------
typedef __attribute__((address_space(1))) void as1_void;
typedef __attribute__((address_space(3))) void as3_void;

__device__ __forceinline__ void gload_lds16(const void* g, void* l) {
    // 16B direct global->LDS; dest is wave-uniform base + lane*16
    __builtin_amdgcn_global_load_lds((as1_void*)(void*)g, (as3_void*)l, 16, 0, 0);
}

// LDS tiles are [rows][64] bf16 (128B rows), XOR-swizzled: byte ^= (row&7)<<4
__device__ __forceinline__ bf16x8 frag_load(const unsigned short* base, int row, int kbyte) {
    kbyte ^= (row & 7) << 4;
    return *reinterpret_cast<const bf16x8*>(reinterpret_cast<const char*>(base) + row * 128 + kbyte);
}

// ---------------- GEMM1: chol = x @ W^T + b, diag-ReLU, store bf16 ----------------
// Swapped-operand MFMA (mfma(B,A)): acc regs hold 4 consecutive n at fixed m
// -> 8B chol stores, table-driven bias/ReLU (no sqrt in epilogue).
__global__ __launch_bounds__(256) void gemm_kernel(const unsigned short* __restrict__ xb,
                                                   const unsigned short* __restrict__ wb,
                                                   const float* __restrict__ biasf,
                                                   const float* __restrict__ diagm,
                                                   unsigned short* __restrict__ chol) {
    __shared__ __align__(16) unsigned short As[128 * 64];
    __shared__ __align__(16) unsigned short Bs[128 * 64];
    const int tid  = threadIdx.x;
    const int lane = tid & 63;
    const int wave = tid >> 6;

    // XCD-aware decode: grid 1088 = 8 XCDs x 136 chunks; XCD x owns m-tiles
    // [8x, 8x+8), n-fastest (A-panels + W stay resident in that XCD's L2).
    const int bid = blockIdx.x;
    const int xcd = bid & 7;
    const int c   = bid >> 3;            // 0..135
    const int mt  = xcd * 8 + c / 17;
    const int nt  = c % 17;
    const int m0 = mt * 128;
    const int n0 = nt * 128;

    const int wm = (wave >> 1) * 64;   // wave row offset in tile
    const int wn = (wave & 1) * 64;    // wave col offset in tile
    const int lr = lane & 15;
    const int lq = lane >> 4;

    f32x4 acc[4][4];
    f32x4 zero = {0.f, 0.f, 0.f, 0.f};
#pragma unroll
    for (int i = 0; i < 4; ++i)
#pragma unroll
        for (int j = 0; j < 4; ++j) acc[i][j] = zero;

    for (int k0 = 0; k0 < KDIM; k0 += 64) {
        const unsigned short* ga = xb + (size_t)m0 * KDIM + k0;
        const unsigned short* gb = wb + (size_t)n0 * KDIM + k0;
        // stage A tile: 128x64 bf16 = 1024 x 16B chunks; pre-swizzled global source
#pragma unroll
        for (int cc = 0; cc < 4; ++cc) {
            int flat = cc * 256 + tid;
            int row  = flat >> 3;
            int ch   = (flat & 7) ^ (row & 7);
            unsigned short* lb = (unsigned short*)As + (size_t)(cc * 256 + (tid & 192)) * 8;
            gload_lds16(ga + row * KDIM + ch * 8, lb);
        }
#pragma unroll
        for (int cc = 0; cc < 4; ++cc) {
            int flat = cc * 256 + tid;
            int row  = flat >> 3;
            int ch   = (flat & 7) ^ (row & 7);
            unsigned short* lb = (unsigned short*)Bs + (size_t)(cc * 256 + (tid & 192)) * 8;
            gload_lds16(gb + row * KDIM + ch * 8, lb);
        }
        __syncthreads();   // drains vmcnt -> staged data visible
#pragma unroll
        for (int kk = 0; kk < 2; ++kk) {
            bf16x8 af[4], bf[4];
            int kb = kk * 64 + lq * 16;
#pragma unroll
            for (int i = 0; i < 4; ++i) {
                af[i] = frag_load(As, wm + i * 16 + lr, kb);
                bf[i] = frag_load(Bs, wn + i * 16 + lr, kb);
            }
#pragma unroll
            for (int mi = 0; mi < 4; ++mi)
#pragma unroll
                for (int ni = 0; ni < 4; ++ni)
                    acc[mi][ni] = __builtin_amdgcn_mfma_f32_16x16x32_bf16(bf[ni], af[mi], acc[mi][ni], 0, 0, 0);
        }
        __syncthreads();   // all waves done reading before next stage overwrites
    }

    // epilogue: acc[mi][ni] reg r -> chol[m][nb+r], m = m0+wm+mi*16+lr,
    // nb = n0+wn+ni*16+lq*4 (4-aligned -> float4 table loads, ushort4 store)
    const float4* bt = reinterpret_cast<const float4*>(biasf);
    const float4* dt = reinterpret_cast<const float4*>(diagm);
#pragma unroll
    for (int ni = 0; ni < 4; ++ni) {
        int nb = n0 + wn + ni * 16 + lq * 4;
        float4 bv = bt[nb >> 2];
        float4 dm = dt[nb >> 2];
#pragma unroll
        for (int mi = 0; mi < 4; ++mi) {
            int m = m0 + wm + mi * 16 + lr;
            float v0 = acc[mi][ni][0] + bv.x; if (dm.x != 0.f && v0 < 0.f) v0 = 0.f;
            float v1 = acc[mi][ni][1] + bv.y; if (dm.y != 0.f && v1 < 0.f) v1 = 0.f;
            float v2 = acc[mi][ni][2] + bv.z; if (dm.z != 0.f && v2 < 0.f) v2 = 0.f;
            float v3 = acc[mi][ni][3] + bv.w; if (dm.w != 0.f && v3 < 0.f) v3 = 0.f;
            *reinterpret_cast<ushort4*>(&chol[(size_t)m * NPAD + nb]) =
                make_ushort4(f2bf(v0), f2bf(v1), f2bf(v2), f2bf(v3));
        }
    }
}

// ---------------- SYRK: out[b] = L @ L^T ----------------
__device__ __forceinline__ void lds_store_swz(unsigned short* L, int i, int j, unsigned short v) {
    int ch   = ((j >> 3) ^ i) & 7;                       // swizzled 16B chunk
    int addr = i * 128 + (ch << 4) + ((j & 7) * 2);
    *reinterpret_cast<unsigned short*>(reinterpret_cast<char*>(L) + addr) = v;
}

__global__ __launch_bounds__(256) void syrk_kernel(const unsigned short* __restrict__ chol,
                                                   float* __restrict__ out) {
    __shared__ __align__(16) unsigned short Ls[4][64 * 64];
    const int tid  = threadIdx.x;
    const int lane = tid & 63;
    const int wave = tid >> 6;

    // XCD affinity with GEMM: XCD x handled batches [1024x, 1024x+1024) there;
    // read chol from the L2 that wrote it. 2048 blocks = 8 x 256.
    const int bid = blockIdx.x;
    const int bb  = (bid & 7) * 256 + (bid >> 3);
    const int batch = bb * 4 + wave;
    unsigned short* L = Ls[wave];

    // Issue all chol-row loads up front (static-indexed reg array; one vmcnt
    // wait instead of 17 serial load->use latencies). 1040 dwords / 64 lanes.
    const unsigned int* row = reinterpret_cast<const unsigned int*>(chol + (size_t)batch * NPAD);
    unsigned int vals[17];
#pragma unroll
    for (int c = 0; c < 17; ++c) {
        int t = lane + c * 64;
        vals[c] = (t < TDIM / 2) ? row[t] : 0u;
    }

    // zero the tile (upper triangle must be 0) — wave-local LDS only
#pragma unroll
    for (int c = 0; c < 8; ++c)
        *reinterpret_cast<int4*>(reinterpret_cast<char*>(L) + (c * 64 + lane) * 16) = make_int4(0, 0, 0, 0);
    __builtin_amdgcn_sched_barrier(0);   // pin zero-writes before scatter-writes

    // scatter chol row into lower triangle
#pragma unroll
    for (int c = 0; c < 17; ++c) {
        int t = lane + c * 64;
        if (t < TDIM / 2) {
            unsigned int v = vals[c];
            int n = 2 * t;
            int i = tril_row(n);
            int j = n - i * (i + 1) / 2;
            lds_store_swz(L, i, j, (unsigned short)(v & 0xffffu));
            int i2 = i, j2 = j + 1;
            if (j2 > i2) { i2 = i + 1; j2 = 0; }
            lds_store_swz(L, i2, j2, (unsigned short)(v >> 16));
        }
    }
    // wave-local write->read ordering (no inter-wave sharing -> no s_barrier)
    asm volatile("s_waitcnt lgkmcnt(0)" ::: "memory");
    __builtin_amdgcn_sched_barrier(0);

    const int lr = lane & 15;
    const int lq = lane >> 4;
    // A and B fragments are identical reads (out = L @ L^T, B^T-form)
    bf16x8 fr[4][2];
#pragma unroll
    for (int i = 0; i < 4; ++i)
#pragma unroll
        for (int kk = 0; kk < 2; ++kk)
            fr[i][kk] = frag_load(L, i * 16 + lr, kk * 64 + lq * 16);

    f32x4 acc[4][4];
    f32x4 zero = {0.f, 0.f, 0.f, 0.f};
#pragma unroll
    for (int i = 0; i < 4; ++i)
#pragma unroll
        for (int j = 0; j < 4; ++j) acc[i][j] = zero;

#pragma unroll
    for (int mi = 0; mi < 4; ++mi)
#pragma unroll
        for (int ni = 0; ni < 4; ++ni)
#pragma unroll
            for (int kk = 0; kk < 2; ++kk)
                acc[mi][ni] = __builtin_amdgcn_mfma_f32_16x16x32_bf16(fr[mi][kk], fr[ni][kk], acc[mi][ni], 0, 0, 0);

    // out is symmetric: store acc[mi][ni] at the TRANSPOSED location so the 4
    // accumulator regs are contiguous -> 16x global_store_dwordx4
    float* ob = out + (size_t)batch * (MSZ * MSZ);
#pragma unroll
    for (int mi = 0; mi < 4; ++mi)
#pragma unroll
        for (int ni = 0; ni < 4; ++ni)
            *reinterpret_cast<f32x4*>(ob + (ni * 16 + lr) * MSZ + mi * 16 + lq * 4) = acc[mi][ni];
}

// ---------------- launch ----------------
extern "C" void kernel_launch(void* const* d_in, const int* in_sizes, int n_in,
                              void* d_out, int out_size, void* d_ws, size_t ws_size,
                              hipStream_t stream) {
    (void)in_sizes; (void)n_in; (void)out_size; (void)ws_size;
    const float* x = (const float*)d_in[0];   // [8192,512]
    const float* W = (const float*)d_in[1];   // [2080,512]
    const float* b = (const float*)d_in[2];   // [2080]
    float* out = (float*)d_out;               // [8192,64,64]

    unsigned short* xb   = (unsigned short*)d_ws;                 // 8192*512 bf16
    unsigned short* wb   = xb + (size_t)MDIM * KDIM;              // 2176*512 bf16 (padded)
    unsigned short* chol = wb + (size_t)NPAD * KDIM;              // 8192*2176 bf16
    float* biasf = (float*)(chol + (size_t)MDIM * NPAD);          // 2176 f32
    float* diagm = biasf + NPAD;                                  // 2176 f32

    int conv_blocks = (NX4 + NW4 + NT4 + 255) / 256;
    convert_kernel<<<dim3(conv_blocks), dim3(256), 0, stream>>>(x, W, b, xb, wb, biasf, diagm);
    gemm_kernel<<<dim3(17 * 64), dim3(256), 0, stream>>>(xb, wb, biasf, diagm, chol);
    syrk_kernel<<<dim3(MDIM / 4), dim3(256), 0, stream>>>(chol, out);
}